// Round 1
// baseline (3217.776 us; speedup 1.0000x reference)
//
#include <hip/hip_runtime.h>

#define N_NODES 50000
#define N_EDGES 800000
#define D       128
#define NPB     64      // nodes per block
#define THREADS 256
#define EPS     1e-5f

// ---------------- CSR build ----------------

__global__ void count_kernel(const int* __restrict__ dst, int* __restrict__ deg) {
    int e = blockIdx.x * 256 + threadIdx.x;
    if (e < N_EDGES) atomicAdd(&deg[dst[e]], 1);
}

__global__ __launch_bounds__(1024) void scan_kernel(const int* __restrict__ deg,
                                                    int* __restrict__ row_start,
                                                    int* __restrict__ cursor) {
    __shared__ int part[1024];
    const int t = threadIdx.x;
    const int CH = (N_NODES + 1023) / 1024;   // 49
    const int base = t * CH;
    int s = 0;
    for (int i = 0; i < CH; ++i) {
        int idx = base + i;
        if (idx < N_NODES) s += deg[idx];
    }
    part[t] = s;
    __syncthreads();
    for (int off = 1; off < 1024; off <<= 1) {
        int add = (t >= off) ? part[t - off] : 0;
        __syncthreads();
        part[t] += add;
        __syncthreads();
    }
    int run = (t == 0) ? 0 : part[t - 1];     // exclusive base
    for (int i = 0; i < CH; ++i) {
        int idx = base + i;
        if (idx < N_NODES) {
            row_start[idx] = run;
            cursor[idx]    = run;
            run += deg[idx];
        }
    }
    if (t == 1023) row_start[N_NODES] = run;  // = N_EDGES
}

__global__ void fill_kernel(const int* __restrict__ src, const int* __restrict__ dst,
                            int* __restrict__ cursor,
                            int* __restrict__ ssrc, int* __restrict__ sdst) {
    int e = blockIdx.x * 256 + threadIdx.x;
    if (e < N_EDGES) {
        int d = dst[e];
        int p = atomicAdd(&cursor[d], 1);
        ssrc[p] = src[e];
        sdst[p] = d;
    }
}

// ---------------- fused SAGE layer ----------------
// Block: 256 threads (4 waves), owns 64 destination nodes.
// Phase 1: CSR edge range -> mean aggregation into swizzled LDS (ds_add_f32).
// Phase 2: out = mean@Wl^T + bl + h@Wr^T, weights via wave-uniform SGPR loads.
// Phase 3: LayerNorm (cross-wave LDS reduce) -> ReLU -> +h residual -> store.

__global__ __launch_bounds__(THREADS, 3)
void layer_kernel(const float* __restrict__ h,
                  float* __restrict__ h_out,
                  const int* __restrict__ row_start,
                  const int* __restrict__ ssrc,
                  const int* __restrict__ sdst,
                  const float* __restrict__ Wl,
                  const float* __restrict__ bl,
                  const float* __restrict__ Wr,
                  const float* __restrict__ gamma,
                  const float* __restrict__ beta) {
    __shared__ float mean_s[(NPB + 1) * D];   // +1 trash row for predication-free tail
    __shared__ float red_s[4][NPB][2];

    const int tid  = threadIdx.x;
    const int lane = tid & 63;
    const int wave = tid >> 6;
    const int n0   = blockIdx.x * NPB;

    // zero accumulation buffer (incl. trash row)
    for (int i = tid; i < (NPB + 1) * D; i += THREADS) mean_s[i] = 0.f;
    __syncthreads();

    // ---- Phase 1: aggregation ----
    const int e0 = row_start[n0];
    const int e1 = row_start[min(n0 + NPB, N_NODES)];
    const int nE = e1 - e0;
    const int per = (nE + 3) >> 2;
    const int wbeg = e0 + wave * per;
    const int wend = min(wbeg + per, e1);

    for (int c = wbeg; c < wend; c += 64) {
        const int cnt = wend - c;             // >=1; may exceed 64 (then all lanes valid)
        int idx = c + lane;
        int srcv, ndv;
        if (lane < cnt) {
            srcv = ssrc[idx];
            ndv  = sdst[idx] - n0;            // 0..63
        } else {
            srcv = ssrc[e0];                  // any valid edge
            ndv  = NPB;                       // trash row
        }
        #pragma unroll 8
        for (int i = 0; i < 64; ++i) {
            int s  = __shfl(srcv, i);
            int nd = __shfl(ndv, i);
            // lanes cover k = 2*lane, 2*lane+1 : one coalesced 512B row read per edge
            float2 v = *reinterpret_cast<const float2*>(h + (size_t)s * D + 2 * lane);
            int pg = (lane >> 1) ^ (nd & 7);  // XOR-swizzled 16B granule
            float* p = mean_s + nd * D + pg * 4 + ((2 * lane) & 3);
            atomicAdd(p, v.x);
            atomicAdd(p + 1, v.y);
        }
    }
    __syncthreads();

    // divide by degree (swizzle-agnostic elementwise)
    for (int i = tid; i < NPB * D; i += THREADS) {
        int n = n0 + (i >> 7);
        if (n < N_NODES) {
            int dg = row_start[n + 1] - row_start[n];
            mean_s[i] /= (float)max(dg, 1);
        }
    }
    __syncthreads();

    // ---- Phase 2: GEMM ----
    const int jbu = __builtin_amdgcn_readfirstlane(wave * 32);   // wave-uniform j-tile base
    const float* __restrict__ Wlb = Wl + jbu * D;
    const float* __restrict__ Wrb = Wr + jbu * D;

    const int node  = n0 + lane;
    const int nodec = min(node, N_NODES - 1);
    const float* hrow = h + (size_t)nodec * D;
    const float* mrow = mean_s + lane * D;

    float acc[32];
    #pragma unroll
    for (int jj = 0; jj < 32; ++jj) acc[jj] = bl[jbu + jj];

    #pragma unroll 1
    for (int kc = 0; kc < D; kc += 16) {
        float4 m[4], x[4];
        #pragma unroll
        for (int q = 0; q < 4; ++q) {
            int pg = ((kc >> 2) + q) ^ (lane & 7);
            m[q] = *reinterpret_cast<const float4*>(mrow + pg * 4);
            x[q] = *reinterpret_cast<const float4*>(hrow + kc + q * 4);
        }
        #pragma unroll
        for (int jj = 0; jj < 32; ++jj) {
            const float* wl4 = Wlb + jj * D + kc;   // uniform -> s_load
            const float* wr4 = Wrb + jj * D + kc;
            float a = acc[jj];
            #pragma unroll
            for (int q = 0; q < 4; ++q) {
                #pragma unroll
                for (int cc = 0; cc < 4; ++cc) {
                    a = fmaf(((const float*)&m[q])[cc], wl4[q * 4 + cc], a);
                    a = fmaf(((const float*)&x[q])[cc], wr4[q * 4 + cc], a);
                }
            }
            acc[jj] = a;
        }
    }

    // ---- Phase 3: LayerNorm + ReLU + residual ----
    float sum = 0.f, sq = 0.f;
    #pragma unroll
    for (int jj = 0; jj < 32; ++jj) {
        sum += acc[jj];
        sq   = fmaf(acc[jj], acc[jj], sq);
    }
    red_s[wave][lane][0] = sum;
    red_s[wave][lane][1] = sq;
    __syncthreads();
    float ts = 0.f, tq = 0.f;
    #pragma unroll
    for (int w2 = 0; w2 < 4; ++w2) {
        ts += red_s[w2][lane][0];
        tq += red_s[w2][lane][1];
    }
    const float mu   = ts * (1.f / 128.f);
    const float var  = fmaf(tq, 1.f / 128.f, -mu * mu);
    const float rstd = 1.f / sqrtf(var + EPS);

    if (node < N_NODES) {
        float* orow = h_out + (size_t)node * D + jbu;
        const float* hres = hrow + jbu;
        #pragma unroll
        for (int q = 0; q < 8; ++q) {
            float4 hv = *reinterpret_cast<const float4*>(hres + q * 4);
            float4 o;
            #pragma unroll
            for (int cc = 0; cc < 4; ++cc) {
                int jj = q * 4 + cc;
                float v = (acc[jj] - mu) * rstd * gamma[jbu + jj] + beta[jbu + jj];
                v = fmaxf(v, 0.f);
                ((float*)&o)[cc] = ((const float*)&hv)[cc] + v;
            }
            *reinterpret_cast<float4*>(orow + q * 4) = o;
        }
    }
}

// ---------------- launch ----------------

extern "C" void kernel_launch(void* const* d_in, const int* in_sizes, int n_in,
                              void* d_out, int out_size, void* d_ws, size_t ws_size,
                              hipStream_t stream) {
    const float* nf = (const float*)d_in[0];
    const int*   ei = (const int*)d_in[1];        // [2][E]: src row, dst row
    const float* Wl = (const float*)d_in[2];      // [3][128][128]
    const float* bl = (const float*)d_in[3];      // [3][128]
    const float* Wr = (const float*)d_in[4];
    const float* gm = (const float*)d_in[5];
    const float* bt = (const float*)d_in[6];
    float* out = (float*)d_out;

    char* w = (char*)d_ws;
    size_t off = 0;
    auto carve = [&](size_t bytes) -> char* {
        char* p = w + off;
        off = (off + bytes + 511) & ~(size_t)511;
        return p;
    };
    int*   deg       = (int*)carve((size_t)N_NODES * 4);
    int*   row_start = (int*)carve((size_t)(N_NODES + 1) * 4);
    int*   cursor    = (int*)carve((size_t)N_NODES * 4);
    int*   ssrc      = (int*)carve((size_t)N_EDGES * 4);
    int*   sdst      = (int*)carve((size_t)N_EDGES * 4);
    float* hA        = (float*)carve((size_t)N_NODES * D * 4);
    float* hB        = (float*)carve((size_t)N_NODES * D * 4);

    const int* src = ei;
    const int* dst = ei + N_EDGES;

    hipMemsetAsync(deg, 0, (size_t)N_NODES * 4, stream);
    count_kernel<<<(N_EDGES + 255) / 256, 256, 0, stream>>>(dst, deg);
    scan_kernel<<<1, 1024, 0, stream>>>(deg, row_start, cursor);
    fill_kernel<<<(N_EDGES + 255) / 256, 256, 0, stream>>>(src, dst, cursor, ssrc, sdst);

    const int GB = (N_NODES + NPB - 1) / NPB;   // 782
    layer_kernel<<<GB, THREADS, 0, stream>>>(nf, hA, row_start, ssrc, sdst,
                                             Wl, bl, Wr, gm, bt);
    layer_kernel<<<GB, THREADS, 0, stream>>>(hA, hB, row_start, ssrc, sdst,
                                             Wl + D * D, bl + D, Wr + D * D, gm + D, bt + D);
    layer_kernel<<<GB, THREADS, 0, stream>>>(hB, out, row_start, ssrc, sdst,
                                             Wl + 2 * D * D, bl + 2 * D, Wr + 2 * D * D,
                                             gm + 2 * D, bt + 2 * D);
}

// Round 2
// 1207.238 us; speedup vs baseline: 2.6654x; 2.6654x over previous
//
#include <hip/hip_runtime.h>

#define N_NODES 50000
#define N_EDGES 800000
#define D       128
#define NPB     64      // nodes per block
#define THREADS 256
#define EPS     1e-5f

// ---------------- CSR build ----------------

__global__ void count_kernel(const int* __restrict__ dst, int* __restrict__ deg) {
    int e = blockIdx.x * 256 + threadIdx.x;
    if (e < N_EDGES) atomicAdd(&deg[dst[e]], 1);
}

__global__ __launch_bounds__(1024) void scan_kernel(const int* __restrict__ deg,
                                                    int* __restrict__ row_start,
                                                    int* __restrict__ cursor) {
    __shared__ int part[1024];
    const int t = threadIdx.x;
    const int CH = (N_NODES + 1023) / 1024;   // 49
    const int base = t * CH;
    int s = 0;
    for (int i = 0; i < CH; ++i) {
        int idx = base + i;
        if (idx < N_NODES) s += deg[idx];
    }
    part[t] = s;
    __syncthreads();
    for (int off = 1; off < 1024; off <<= 1) {
        int add = (t >= off) ? part[t - off] : 0;
        __syncthreads();
        part[t] += add;
        __syncthreads();
    }
    int run = (t == 0) ? 0 : part[t - 1];     // exclusive base
    for (int i = 0; i < CH; ++i) {
        int idx = base + i;
        if (idx < N_NODES) {
            row_start[idx] = run;
            cursor[idx]    = run;
            run += deg[idx];
        }
    }
    if (t == 1023) row_start[N_NODES] = run;  // = N_EDGES
}

__global__ void fill_kernel(const int* __restrict__ src, const int* __restrict__ dst,
                            int* __restrict__ cursor, int* __restrict__ ssrc) {
    int e = blockIdx.x * 256 + threadIdx.x;
    if (e < N_EDGES) {
        int d = dst[e];
        int p = atomicAdd(&cursor[d], 1);
        ssrc[p] = src[e];
    }
}

// ---------------- fused SAGE layer ----------------
// Block: 256 threads (4 waves), owns 64 destination nodes.
// Phase 1: wave-per-node register aggregation (1 coalesced dwordx2 row-load
//          per edge, scalar edge indices), swizzled ds_write of the mean.
// Phase 2: out = mean@Wl^T + bl + h@Wr^T; lane=node, wave=32-col j-tile,
//          weights via uniform-address (scalar) float4 loads. No address-
//          taking of register arrays anywhere (keeps SROA happy).
// Phase 3: LayerNorm (cross-wave LDS reduce) -> ReLU -> +h residual -> store.

__global__ __launch_bounds__(THREADS, 4)
void layer_kernel(const float* __restrict__ h,
                  float* __restrict__ h_out,
                  const int* __restrict__ row_start,
                  const int* __restrict__ ssrc,
                  const float* __restrict__ Wl,
                  const float* __restrict__ bl,
                  const float* __restrict__ Wr,
                  const float* __restrict__ gamma,
                  const float* __restrict__ beta) {
    __shared__ float mean_s[NPB * D];
    __shared__ float red_s[4][NPB][2];

    const int tid  = threadIdx.x;
    const int lane = tid & 63;
    const int wave = tid >> 6;
    const int n0   = blockIdx.x * NPB;

    // ---- Phase 1: aggregation (wave handles 16 nodes, lane covers k=2l,2l+1)
    #pragma unroll 1
    for (int i = 0; i < 16; ++i) {
        const int nd = wave * 16 + i;                  // 0..63
        const int n  = n0 + nd;
        const int nc = min(n, N_NODES - 1);
        const int e0 = __builtin_amdgcn_readfirstlane(row_start[nc]);
        const int e1 = __builtin_amdgcn_readfirstlane(row_start[nc + 1]);
        float a0 = 0.f, a1 = 0.f;
        #pragma unroll 4
        for (int e = e0; e < e1; ++e) {
            const int s = ssrc[e];                     // uniform -> s_load
            const float2 v = *reinterpret_cast<const float2*>(h + (size_t)s * D + 2 * lane);
            a0 += v.x;
            a1 += v.y;
        }
        const float inv = 1.f / (float)max(e1 - e0, 1);
        const int pg = (lane >> 1) ^ (nd & 7);         // XOR-swizzled 16B granule
        float2 mv;
        mv.x = a0 * inv;
        mv.y = a1 * inv;
        *reinterpret_cast<float2*>(mean_s + nd * D + pg * 4 + ((2 * lane) & 3)) = mv;
    }
    __syncthreads();

    // ---- Phase 2: GEMM ----
    const int jb = wave * 32;                          // wave-uniform j-tile base
    const float* __restrict__ Wlb = Wl + jb * D;
    const float* __restrict__ Wrb = Wr + jb * D;

    const int node  = n0 + lane;
    const int nodec = min(node, N_NODES - 1);
    const float* __restrict__ hrow = h + (size_t)nodec * D;
    const float* __restrict__ mrow = mean_s + lane * D;

    float acc[32];
    #pragma unroll
    for (int jj = 0; jj < 32; ++jj) acc[jj] = bl[jb + jj];

    #pragma unroll 1
    for (int kc = 0; kc < D; kc += 16) {
        const int b = kc >> 2;
        const int sw = lane & 7;
        const float4 m0 = *reinterpret_cast<const float4*>(mrow + ((b + 0) ^ sw) * 4);
        const float4 m1 = *reinterpret_cast<const float4*>(mrow + ((b + 1) ^ sw) * 4);
        const float4 m2 = *reinterpret_cast<const float4*>(mrow + ((b + 2) ^ sw) * 4);
        const float4 m3 = *reinterpret_cast<const float4*>(mrow + ((b + 3) ^ sw) * 4);
        const float4 x0 = *reinterpret_cast<const float4*>(hrow + kc);
        const float4 x1 = *reinterpret_cast<const float4*>(hrow + kc + 4);
        const float4 x2 = *reinterpret_cast<const float4*>(hrow + kc + 8);
        const float4 x3 = *reinterpret_cast<const float4*>(hrow + kc + 12);

        #pragma unroll 4
        for (int jj = 0; jj < 32; ++jj) {
            const float* wlp = Wlb + jj * D + kc;      // uniform -> s_load_dwordx4
            const float* wrp = Wrb + jj * D + kc;
            const float4 wl0 = *reinterpret_cast<const float4*>(wlp);
            const float4 wl1 = *reinterpret_cast<const float4*>(wlp + 4);
            const float4 wl2 = *reinterpret_cast<const float4*>(wlp + 8);
            const float4 wl3 = *reinterpret_cast<const float4*>(wlp + 12);
            const float4 wr0 = *reinterpret_cast<const float4*>(wrp);
            const float4 wr1 = *reinterpret_cast<const float4*>(wrp + 4);
            const float4 wr2 = *reinterpret_cast<const float4*>(wrp + 8);
            const float4 wr3 = *reinterpret_cast<const float4*>(wrp + 12);
            float a = acc[jj];
            a = fmaf(m0.x, wl0.x, a); a = fmaf(m0.y, wl0.y, a);
            a = fmaf(m0.z, wl0.z, a); a = fmaf(m0.w, wl0.w, a);
            a = fmaf(m1.x, wl1.x, a); a = fmaf(m1.y, wl1.y, a);
            a = fmaf(m1.z, wl1.z, a); a = fmaf(m1.w, wl1.w, a);
            a = fmaf(m2.x, wl2.x, a); a = fmaf(m2.y, wl2.y, a);
            a = fmaf(m2.z, wl2.z, a); a = fmaf(m2.w, wl2.w, a);
            a = fmaf(m3.x, wl3.x, a); a = fmaf(m3.y, wl3.y, a);
            a = fmaf(m3.z, wl3.z, a); a = fmaf(m3.w, wl3.w, a);
            a = fmaf(x0.x, wr0.x, a); a = fmaf(x0.y, wr0.y, a);
            a = fmaf(x0.z, wr0.z, a); a = fmaf(x0.w, wr0.w, a);
            a = fmaf(x1.x, wr1.x, a); a = fmaf(x1.y, wr1.y, a);
            a = fmaf(x1.z, wr1.z, a); a = fmaf(x1.w, wr1.w, a);
            a = fmaf(x2.x, wr2.x, a); a = fmaf(x2.y, wr2.y, a);
            a = fmaf(x2.z, wr2.z, a); a = fmaf(x2.w, wr2.w, a);
            a = fmaf(x3.x, wr3.x, a); a = fmaf(x3.y, wr3.y, a);
            a = fmaf(x3.z, wr3.z, a); a = fmaf(x3.w, wr3.w, a);
            acc[jj] = a;
        }
    }

    // ---- Phase 3: LayerNorm + ReLU + residual ----
    float sum = 0.f, sq = 0.f;
    #pragma unroll
    for (int jj = 0; jj < 32; ++jj) {
        sum += acc[jj];
        sq   = fmaf(acc[jj], acc[jj], sq);
    }
    red_s[wave][lane][0] = sum;
    red_s[wave][lane][1] = sq;
    __syncthreads();
    float ts = 0.f, tq = 0.f;
    #pragma unroll
    for (int w2 = 0; w2 < 4; ++w2) {
        ts += red_s[w2][lane][0];
        tq += red_s[w2][lane][1];
    }
    const float mu   = ts * (1.f / 128.f);
    const float var  = fmaf(tq, 1.f / 128.f, -mu * mu);
    const float rstd = 1.f / sqrtf(var + EPS);

    if (node < N_NODES) {
        float* orow = h_out + (size_t)node * D + jb;
        const float* hres = hrow + jb;
        #pragma unroll
        for (int q = 0; q < 8; ++q) {
            const float4 hv = *reinterpret_cast<const float4*>(hres + q * 4);
            const float g0 = gamma[jb + q * 4 + 0], b0 = beta[jb + q * 4 + 0];
            const float g1 = gamma[jb + q * 4 + 1], b1 = beta[jb + q * 4 + 1];
            const float g2 = gamma[jb + q * 4 + 2], b2 = beta[jb + q * 4 + 2];
            const float g3 = gamma[jb + q * 4 + 3], b3 = beta[jb + q * 4 + 3];
            float4 o;
            o.x = hv.x + fmaxf((acc[q * 4 + 0] - mu) * rstd * g0 + b0, 0.f);
            o.y = hv.y + fmaxf((acc[q * 4 + 1] - mu) * rstd * g1 + b1, 0.f);
            o.z = hv.z + fmaxf((acc[q * 4 + 2] - mu) * rstd * g2 + b2, 0.f);
            o.w = hv.w + fmaxf((acc[q * 4 + 3] - mu) * rstd * g3 + b3, 0.f);
            *reinterpret_cast<float4*>(orow + q * 4) = o;
        }
    }
}

// ---------------- launch ----------------

extern "C" void kernel_launch(void* const* d_in, const int* in_sizes, int n_in,
                              void* d_out, int out_size, void* d_ws, size_t ws_size,
                              hipStream_t stream) {
    const float* nf = (const float*)d_in[0];
    const int*   ei = (const int*)d_in[1];        // [2][E]: src row, dst row
    const float* Wl = (const float*)d_in[2];      // [3][128][128]
    const float* bl = (const float*)d_in[3];      // [3][128]
    const float* Wr = (const float*)d_in[4];
    const float* gm = (const float*)d_in[5];
    const float* bt = (const float*)d_in[6];
    float* out = (float*)d_out;

    char* w = (char*)d_ws;
    size_t off = 0;
    auto carve = [&](size_t bytes) -> char* {
        char* p = w + off;
        off = (off + bytes + 511) & ~(size_t)511;
        return p;
    };
    int*   deg       = (int*)carve((size_t)N_NODES * 4);
    int*   row_start = (int*)carve((size_t)(N_NODES + 1) * 4);
    int*   cursor    = (int*)carve((size_t)N_NODES * 4);
    int*   ssrc      = (int*)carve((size_t)N_EDGES * 4);
    float* hA        = (float*)carve((size_t)N_NODES * D * 4);
    float* hB        = (float*)carve((size_t)N_NODES * D * 4);

    const int* src = ei;
    const int* dst = ei + N_EDGES;

    hipMemsetAsync(deg, 0, (size_t)N_NODES * 4, stream);
    count_kernel<<<(N_EDGES + 255) / 256, 256, 0, stream>>>(dst, deg);
    scan_kernel<<<1, 1024, 0, stream>>>(deg, row_start, cursor);
    fill_kernel<<<(N_EDGES + 255) / 256, 256, 0, stream>>>(src, dst, cursor, ssrc);

    const int GB = (N_NODES + NPB - 1) / NPB;   // 782
    layer_kernel<<<GB, THREADS, 0, stream>>>(nf, hA, row_start, ssrc,
                                             Wl, bl, Wr, gm, bt);
    layer_kernel<<<GB, THREADS, 0, stream>>>(hA, hB, row_start, ssrc,
                                             Wl + D * D, bl + D, Wr + D * D, gm + D, bt + D);
    layer_kernel<<<GB, THREADS, 0, stream>>>(hB, out, row_start, ssrc,
                                             Wl + 2 * D * D, bl + 2 * D, Wr + 2 * D * D,
                                             gm + 2 * D, bt + 2 * D);
}

// Round 3
// 1190.182 us; speedup vs baseline: 2.7036x; 1.0143x over previous
//
#include <hip/hip_runtime.h>

#define N_NODES 50000
#define N_EDGES 800000
#define D       128
#define NPB     64      // nodes per block
#define THREADS 256
#define EPS     1e-5f

// ---------------- CSR build ----------------

__global__ void count_kernel(const int* __restrict__ dst, int* __restrict__ deg) {
    int e = blockIdx.x * 256 + threadIdx.x;
    if (e < N_EDGES) atomicAdd(&deg[dst[e]], 1);
}

__global__ __launch_bounds__(1024) void scan_kernel(const int* __restrict__ deg,
                                                    int* __restrict__ row_start,
                                                    int* __restrict__ cursor) {
    __shared__ int part[1024];
    const int t = threadIdx.x;
    const int CH = (N_NODES + 1023) / 1024;   // 49
    const int base = t * CH;
    int s = 0;
    for (int i = 0; i < CH; ++i) {
        int idx = base + i;
        if (idx < N_NODES) s += deg[idx];
    }
    part[t] = s;
    __syncthreads();
    for (int off = 1; off < 1024; off <<= 1) {
        int add = (t >= off) ? part[t - off] : 0;
        __syncthreads();
        part[t] += add;
        __syncthreads();
    }
    int run = (t == 0) ? 0 : part[t - 1];     // exclusive base
    for (int i = 0; i < CH; ++i) {
        int idx = base + i;
        if (idx < N_NODES) {
            row_start[idx] = run;
            cursor[idx]    = run;
            run += deg[idx];
        }
    }
    if (t == 1023) row_start[N_NODES] = run;  // = N_EDGES
}

__global__ void fill_kernel(const int* __restrict__ src, const int* __restrict__ dst,
                            int* __restrict__ cursor, int* __restrict__ ssrc) {
    int e = blockIdx.x * 256 + threadIdx.x;
    if (e < N_EDGES) {
        int d = dst[e];
        int p = atomicAdd(&cursor[d], 1);
        ssrc[p] = src[e];
    }
}

// ---------------- fused SAGE layer ----------------
// Block: 256 threads (4 waves), owns 64 destination nodes.
// Phase 1: 4 nodes PER WAVE concurrently (16-lane groups, lane covers 8
//          floats via two dwordx4). 4-edge unroll + index prefetch pipeline
//          -> ~32 outstanding row-loads per wave (MLP for the random gather).
// Phase 2: out = mean@Wl^T + bl + h@Wr^T; lane=node, wave=32-col j-tile,
//          weights via uniform-address scalar float4 loads. Named scalars
//          only (SROA-safe, no address-taking of register arrays).
// Phase 3: LayerNorm (cross-wave reduce via LDS aliased onto mean_s) ->
//          ReLU -> +h residual -> store. LDS = exactly 32KB -> 5 blocks/CU.

__global__ __launch_bounds__(THREADS, 4)
void layer_kernel(const float* __restrict__ h,
                  float* __restrict__ h_out,
                  const int* __restrict__ row_start,
                  const int* __restrict__ ssrc,
                  const float* __restrict__ Wl,
                  const float* __restrict__ bl,
                  const float* __restrict__ Wr,
                  const float* __restrict__ gamma,
                  const float* __restrict__ beta) {
    __shared__ float mean_s[NPB * D];          // 32 KB; reduce scratch aliased below

    const int tid  = threadIdx.x;
    const int lane = tid & 63;
    const int wave = tid >> 6;
    const int n0   = blockIdx.x * NPB;

    // ---- Phase 1: aggregation. Wave handles 16 nodes as 4 quads of 4. ----
    const int g  = lane >> 4;                  // group 0..3 (node within quad)
    const int lg = lane & 15;                  // lane in group: floats 8lg..8lg+7

    #pragma unroll 1
    for (int q = 0; q < 4; ++q) {
        const int nd = wave * 16 + q * 4 + g;  // 0..63
        const int n  = min(n0 + nd, N_NODES - 1);
        int e        = row_start[n];           // uniform within group (vector ld)
        const int e1 = row_start[n + 1];
        const float inv = 1.f / (float)max(e1 - e, 1);

        float a0 = 0.f, a1 = 0.f, a2 = 0.f, a3 = 0.f;
        float a4 = 0.f, a5 = 0.f, a6 = 0.f, a7 = 0.f;

        int s0 = 0, s1 = 0, s2 = 0, s3 = 0;
        if (e + 4 <= e1) { s0 = ssrc[e]; s1 = ssrc[e + 1]; s2 = ssrc[e + 2]; s3 = ssrc[e + 3]; }
        #pragma unroll 1
        while (e + 4 <= e1) {
            const int en = e + 4;
            const int pe = (en + 4 <= e1) ? en : e;   // prefetch next quad (safe addr)
            const int t0 = ssrc[pe];
            const int t1 = ssrc[pe + 1];
            const int t2 = ssrc[pe + 2];
            const int t3 = ssrc[pe + 3];
            const float* p0 = h + (size_t)s0 * D + lg * 8;
            const float* p1 = h + (size_t)s1 * D + lg * 8;
            const float* p2 = h + (size_t)s2 * D + lg * 8;
            const float* p3 = h + (size_t)s3 * D + lg * 8;
            const float4 u0 = *reinterpret_cast<const float4*>(p0);
            const float4 v0 = *reinterpret_cast<const float4*>(p0 + 4);
            const float4 u1 = *reinterpret_cast<const float4*>(p1);
            const float4 v1 = *reinterpret_cast<const float4*>(p1 + 4);
            const float4 u2 = *reinterpret_cast<const float4*>(p2);
            const float4 v2 = *reinterpret_cast<const float4*>(p2 + 4);
            const float4 u3 = *reinterpret_cast<const float4*>(p3);
            const float4 v3 = *reinterpret_cast<const float4*>(p3 + 4);
            a0 += u0.x; a1 += u0.y; a2 += u0.z; a3 += u0.w;
            a4 += v0.x; a5 += v0.y; a6 += v0.z; a7 += v0.w;
            a0 += u1.x; a1 += u1.y; a2 += u1.z; a3 += u1.w;
            a4 += v1.x; a5 += v1.y; a6 += v1.z; a7 += v1.w;
            a0 += u2.x; a1 += u2.y; a2 += u2.z; a3 += u2.w;
            a4 += v2.x; a5 += v2.y; a6 += v2.z; a7 += v2.w;
            a0 += u3.x; a1 += u3.y; a2 += u3.z; a3 += u3.w;
            a4 += v3.x; a5 += v3.y; a6 += v3.z; a7 += v3.w;
            s0 = t0; s1 = t1; s2 = t2; s3 = t3;
            e = en;
        }
        #pragma unroll 1
        while (e < e1) {                        // tail 0..3 edges
            const int s = ssrc[e];
            const float* p = h + (size_t)s * D + lg * 8;
            const float4 u = *reinterpret_cast<const float4*>(p);
            const float4 v = *reinterpret_cast<const float4*>(p + 4);
            a0 += u.x; a1 += u.y; a2 += u.z; a3 += u.w;
            a4 += v.x; a5 += v.y; a6 += v.z; a7 += v.w;
            ++e;
        }

        // swizzled store: granules 2lg, 2lg+1 -> slots (gr ^ (nd&7))
        float4 f0, f1;
        f0.x = a0 * inv; f0.y = a1 * inv; f0.z = a2 * inv; f0.w = a3 * inv;
        f1.x = a4 * inv; f1.y = a5 * inv; f1.z = a6 * inv; f1.w = a7 * inv;
        const int sw = nd & 7;
        *reinterpret_cast<float4*>(mean_s + nd * D + ((2 * lg) ^ sw) * 4)     = f0;
        *reinterpret_cast<float4*>(mean_s + nd * D + ((2 * lg + 1) ^ sw) * 4) = f1;
    }
    __syncthreads();

    // ---- Phase 2: GEMM ----
    const int jb = wave * 32;                          // wave-uniform j-tile base
    const float* __restrict__ Wlb = Wl + jb * D;
    const float* __restrict__ Wrb = Wr + jb * D;

    const int node  = n0 + lane;
    const int nodec = min(node, N_NODES - 1);
    const float* __restrict__ hrow = h + (size_t)nodec * D;
    const float* __restrict__ mrow = mean_s + lane * D;

    float acc[32];
    #pragma unroll
    for (int jj = 0; jj < 32; ++jj) acc[jj] = bl[jb + jj];

    #pragma unroll 1
    for (int kc = 0; kc < D; kc += 16) {
        const int b = kc >> 2;
        const int sw = lane & 7;
        const float4 m0 = *reinterpret_cast<const float4*>(mrow + ((b + 0) ^ sw) * 4);
        const float4 m1 = *reinterpret_cast<const float4*>(mrow + ((b + 1) ^ sw) * 4);
        const float4 m2 = *reinterpret_cast<const float4*>(mrow + ((b + 2) ^ sw) * 4);
        const float4 m3 = *reinterpret_cast<const float4*>(mrow + ((b + 3) ^ sw) * 4);
        const float4 x0 = *reinterpret_cast<const float4*>(hrow + kc);
        const float4 x1 = *reinterpret_cast<const float4*>(hrow + kc + 4);
        const float4 x2 = *reinterpret_cast<const float4*>(hrow + kc + 8);
        const float4 x3 = *reinterpret_cast<const float4*>(hrow + kc + 12);

        #pragma unroll 4
        for (int jj = 0; jj < 32; ++jj) {
            const float* wlp = Wlb + jj * D + kc;      // uniform -> s_load_dwordx4
            const float* wrp = Wrb + jj * D + kc;
            const float4 wl0 = *reinterpret_cast<const float4*>(wlp);
            const float4 wl1 = *reinterpret_cast<const float4*>(wlp + 4);
            const float4 wl2 = *reinterpret_cast<const float4*>(wlp + 8);
            const float4 wl3 = *reinterpret_cast<const float4*>(wlp + 12);
            const float4 wr0 = *reinterpret_cast<const float4*>(wrp);
            const float4 wr1 = *reinterpret_cast<const float4*>(wrp + 4);
            const float4 wr2 = *reinterpret_cast<const float4*>(wrp + 8);
            const float4 wr3 = *reinterpret_cast<const float4*>(wrp + 12);
            float a = acc[jj];
            a = fmaf(m0.x, wl0.x, a); a = fmaf(m0.y, wl0.y, a);
            a = fmaf(m0.z, wl0.z, a); a = fmaf(m0.w, wl0.w, a);
            a = fmaf(m1.x, wl1.x, a); a = fmaf(m1.y, wl1.y, a);
            a = fmaf(m1.z, wl1.z, a); a = fmaf(m1.w, wl1.w, a);
            a = fmaf(m2.x, wl2.x, a); a = fmaf(m2.y, wl2.y, a);
            a = fmaf(m2.z, wl2.z, a); a = fmaf(m2.w, wl2.w, a);
            a = fmaf(m3.x, wl3.x, a); a = fmaf(m3.y, wl3.y, a);
            a = fmaf(m3.z, wl3.z, a); a = fmaf(m3.w, wl3.w, a);
            a = fmaf(x0.x, wr0.x, a); a = fmaf(x0.y, wr0.y, a);
            a = fmaf(x0.z, wr0.z, a); a = fmaf(x0.w, wr0.w, a);
            a = fmaf(x1.x, wr1.x, a); a = fmaf(x1.y, wr1.y, a);
            a = fmaf(x1.z, wr1.z, a); a = fmaf(x1.w, wr1.w, a);
            a = fmaf(x2.x, wr2.x, a); a = fmaf(x2.y, wr2.y, a);
            a = fmaf(x2.z, wr2.z, a); a = fmaf(x2.w, wr2.w, a);
            a = fmaf(x3.x, wr3.x, a); a = fmaf(x3.y, wr3.y, a);
            a = fmaf(x3.z, wr3.z, a); a = fmaf(x3.w, wr3.w, a);
            acc[jj] = a;
        }
    }

    // ---- Phase 3: LayerNorm + ReLU + residual ----
    float sum = 0.f, sq = 0.f;
    #pragma unroll
    for (int jj = 0; jj < 32; ++jj) {
        sum += acc[jj];
        sq   = fmaf(acc[jj], acc[jj], sq);
    }
    __syncthreads();                            // mean_s dead -> reuse as scratch
    float* red_s = mean_s;                      // [4][64][2]
    red_s[(wave * 64 + lane) * 2 + 0] = sum;
    red_s[(wave * 64 + lane) * 2 + 1] = sq;
    __syncthreads();
    float ts = 0.f, tq = 0.f;
    #pragma unroll
    for (int w2 = 0; w2 < 4; ++w2) {
        ts += red_s[(w2 * 64 + lane) * 2 + 0];
        tq += red_s[(w2 * 64 + lane) * 2 + 1];
    }
    const float mu   = ts * (1.f / 128.f);
    const float var  = fmaf(tq, 1.f / 128.f, -mu * mu);
    const float rstd = 1.f / sqrtf(var + EPS);

    if (node < N_NODES) {
        float* orow = h_out + (size_t)node * D + jb;
        const float* hres = hrow + jb;
        #pragma unroll
        for (int q = 0; q < 8; ++q) {
            const float4 hv = *reinterpret_cast<const float4*>(hres + q * 4);
            const float g0 = gamma[jb + q * 4 + 0], b0 = beta[jb + q * 4 + 0];
            const float g1 = gamma[jb + q * 4 + 1], b1 = beta[jb + q * 4 + 1];
            const float g2 = gamma[jb + q * 4 + 2], b2 = beta[jb + q * 4 + 2];
            const float g3 = gamma[jb + q * 4 + 3], b3 = beta[jb + q * 4 + 3];
            float4 o;
            o.x = hv.x + fmaxf((acc[q * 4 + 0] - mu) * rstd * g0 + b0, 0.f);
            o.y = hv.y + fmaxf((acc[q * 4 + 1] - mu) * rstd * g1 + b1, 0.f);
            o.z = hv.z + fmaxf((acc[q * 4 + 2] - mu) * rstd * g2 + b2, 0.f);
            o.w = hv.w + fmaxf((acc[q * 4 + 3] - mu) * rstd * g3 + b3, 0.f);
            *reinterpret_cast<float4*>(orow + q * 4) = o;
        }
    }
}

// ---------------- launch ----------------

extern "C" void kernel_launch(void* const* d_in, const int* in_sizes, int n_in,
                              void* d_out, int out_size, void* d_ws, size_t ws_size,
                              hipStream_t stream) {
    const float* nf = (const float*)d_in[0];
    const int*   ei = (const int*)d_in[1];        // [2][E]: src row, dst row
    const float* Wl = (const float*)d_in[2];      // [3][128][128]
    const float* bl = (const float*)d_in[3];      // [3][128]
    const float* Wr = (const float*)d_in[4];
    const float* gm = (const float*)d_in[5];
    const float* bt = (const float*)d_in[6];
    float* out = (float*)d_out;

    char* w = (char*)d_ws;
    size_t off = 0;
    auto carve = [&](size_t bytes) -> char* {
        char* p = w + off;
        off = (off + bytes + 511) & ~(size_t)511;
        return p;
    };
    int*   deg       = (int*)carve((size_t)N_NODES * 4);
    int*   row_start = (int*)carve((size_t)(N_NODES + 1) * 4);
    int*   cursor    = (int*)carve((size_t)N_NODES * 4);
    int*   ssrc      = (int*)carve((size_t)N_EDGES * 4);
    float* hA        = (float*)carve((size_t)N_NODES * D * 4);
    float* hB        = (float*)carve((size_t)N_NODES * D * 4);

    const int* src = ei;
    const int* dst = ei + N_EDGES;

    hipMemsetAsync(deg, 0, (size_t)N_NODES * 4, stream);
    count_kernel<<<(N_EDGES + 255) / 256, 256, 0, stream>>>(dst, deg);
    scan_kernel<<<1, 1024, 0, stream>>>(deg, row_start, cursor);
    fill_kernel<<<(N_EDGES + 255) / 256, 256, 0, stream>>>(src, dst, cursor, ssrc);

    const int GB = (N_NODES + NPB - 1) / NPB;   // 782
    layer_kernel<<<GB, THREADS, 0, stream>>>(nf, hA, row_start, ssrc,
                                             Wl, bl, Wr, gm, bt);
    layer_kernel<<<GB, THREADS, 0, stream>>>(hA, hB, row_start, ssrc,
                                             Wl + D * D, bl + D, Wr + D * D, gm + D, bt + D);
    layer_kernel<<<GB, THREADS, 0, stream>>>(hB, out, row_start, ssrc,
                                             Wl + 2 * D * D, bl + 2 * D, Wr + 2 * D * D,
                                             gm + 2 * D, bt + 2 * D);
}

// Round 4
// 1138.215 us; speedup vs baseline: 2.8270x; 1.0457x over previous
//
#include <hip/hip_runtime.h>

#define N_NODES 50000
#define N_EDGES 800000
#define D       128
#define NPB     64      // nodes per block (gemm kernel)
#define THREADS 256
#define EPS     1e-5f
#define SCAN_B  196     // ceil(N_NODES/256)

// ---------------- CSR build ----------------

__global__ void count_kernel(const int* __restrict__ dst, int* __restrict__ deg) {
    int e = blockIdx.x * 256 + threadIdx.x;
    if (e < N_EDGES) atomicAdd(&deg[dst[e]], 1);
}

__global__ void block_reduce_kernel(const int* __restrict__ deg, int* __restrict__ bsum) {
    __shared__ int red[256];
    int i = blockIdx.x * 256 + threadIdx.x;
    red[threadIdx.x] = (i < N_NODES) ? deg[i] : 0;
    __syncthreads();
    for (int off = 128; off > 0; off >>= 1) {
        if (threadIdx.x < off) red[threadIdx.x] += red[threadIdx.x + off];
        __syncthreads();
    }
    if (threadIdx.x == 0) bsum[blockIdx.x] = red[0];
}

__global__ void block_scan_kernel(const int* __restrict__ bsum, int* __restrict__ bbase) {
    __shared__ int s[256];
    const int t = threadIdx.x;
    const int v = (t < SCAN_B) ? bsum[t] : 0;
    s[t] = v;
    __syncthreads();
    for (int off = 1; off < 256; off <<= 1) {
        int add = (t >= off) ? s[t - off] : 0;
        __syncthreads();
        s[t] += add;
        __syncthreads();
    }
    if (t < SCAN_B) bbase[t] = s[t] - v;   // exclusive
}

__global__ void expand_kernel(const int* __restrict__ deg, const int* __restrict__ bbase,
                              int* __restrict__ row_start, int* __restrict__ cursor) {
    __shared__ int s[256];
    const int t = threadIdx.x;
    const int i = blockIdx.x * 256 + t;
    const int v = (i < N_NODES) ? deg[i] : 0;
    s[t] = v;
    __syncthreads();
    for (int off = 1; off < 256; off <<= 1) {
        int add = (t >= off) ? s[t - off] : 0;
        __syncthreads();
        s[t] += add;
        __syncthreads();
    }
    const int excl = bbase[blockIdx.x] + s[t] - v;
    if (i < N_NODES) { row_start[i] = excl; cursor[i] = excl; }
    if (i == N_NODES - 1) row_start[N_NODES] = excl + v;
}

__global__ void fill_kernel(const int* __restrict__ src, const int* __restrict__ dst,
                            int* __restrict__ cursor, int* __restrict__ ssrc) {
    int e = blockIdx.x * 256 + threadIdx.x;
    if (e < N_EDGES) {
        int d = dst[e];
        int p = atomicAdd(&cursor[d], 1);
        ssrc[p] = src[e];
    }
}

// ---------------- aggregation: mean[n] = avg of h[src] over CSR row n ----
// Wave-per-node, 12500 blocks, no LDS -> up to 32 waves/CU resident.
// Scalar (SGPR) edge indices; 8-edge clamped+weighted chunks (no serial
// tail); lane covers floats 2l,2l+1 -> one coalesced 512B row read/edge.

__global__ __launch_bounds__(256, 8)
void agg_kernel(const float* __restrict__ h, float* __restrict__ mean,
                const int* __restrict__ row_start, const int* __restrict__ ssrc) {
    const int lane = threadIdx.x & 63;
    const int wave = threadIdx.x >> 6;
    const int n = blockIdx.x * 4 + wave;
    if (n >= N_NODES) return;
    const int e0 = __builtin_amdgcn_readfirstlane(row_start[n]);
    const int e1 = __builtin_amdgcn_readfirstlane(row_start[n + 1]);
    const int off = lane * 2;

    float a0 = 0.f, a1 = 0.f;
    #pragma unroll 1
    for (int e = e0; e < e1; e += 8) {
        const int el = e1 - 1;
        const int s0 = ssrc[min(e + 0, el)];
        const int s1 = ssrc[min(e + 1, el)];
        const int s2 = ssrc[min(e + 2, el)];
        const int s3 = ssrc[min(e + 3, el)];
        const int s4 = ssrc[min(e + 4, el)];
        const int s5 = ssrc[min(e + 5, el)];
        const int s6 = ssrc[min(e + 6, el)];
        const int s7 = ssrc[min(e + 7, el)];
        const float2 v0 = *reinterpret_cast<const float2*>(h + (size_t)s0 * D + off);
        const float2 v1 = *reinterpret_cast<const float2*>(h + (size_t)s1 * D + off);
        const float2 v2 = *reinterpret_cast<const float2*>(h + (size_t)s2 * D + off);
        const float2 v3 = *reinterpret_cast<const float2*>(h + (size_t)s3 * D + off);
        const float2 v4 = *reinterpret_cast<const float2*>(h + (size_t)s4 * D + off);
        const float2 v5 = *reinterpret_cast<const float2*>(h + (size_t)s5 * D + off);
        const float2 v6 = *reinterpret_cast<const float2*>(h + (size_t)s6 * D + off);
        const float2 v7 = *reinterpret_cast<const float2*>(h + (size_t)s7 * D + off);
        const float w1 = (e + 1 < e1) ? 1.f : 0.f;
        const float w2 = (e + 2 < e1) ? 1.f : 0.f;
        const float w3 = (e + 3 < e1) ? 1.f : 0.f;
        const float w4 = (e + 4 < e1) ? 1.f : 0.f;
        const float w5 = (e + 5 < e1) ? 1.f : 0.f;
        const float w6 = (e + 6 < e1) ? 1.f : 0.f;
        const float w7 = (e + 7 < e1) ? 1.f : 0.f;
        a0 += v0.x;                 a1 += v0.y;
        a0 = fmaf(v1.x, w1, a0);    a1 = fmaf(v1.y, w1, a1);
        a0 = fmaf(v2.x, w2, a0);    a1 = fmaf(v2.y, w2, a1);
        a0 = fmaf(v3.x, w3, a0);    a1 = fmaf(v3.y, w3, a1);
        a0 = fmaf(v4.x, w4, a0);    a1 = fmaf(v4.y, w4, a1);
        a0 = fmaf(v5.x, w5, a0);    a1 = fmaf(v5.y, w5, a1);
        a0 = fmaf(v6.x, w6, a0);    a1 = fmaf(v6.y, w6, a1);
        a0 = fmaf(v7.x, w7, a0);    a1 = fmaf(v7.y, w7, a1);
    }
    const float inv = 1.f / (float)max(e1 - e0, 1);
    float2 mv;
    mv.x = a0 * inv;
    mv.y = a1 * inv;
    *reinterpret_cast<float2*>(mean + (size_t)n * D + off) = mv;
}

// ---------------- GEMM + LayerNorm + ReLU + residual ----------------
// Block: 256 threads (4 waves), 64 nodes; lane=node, wave=32-col j-tile;
// weights via uniform-address scalar float4 loads; SROA-safe named scalars.

__global__ __launch_bounds__(THREADS, 4)
void gemm_kernel(const float* __restrict__ h,
                 const float* __restrict__ mean,
                 float* __restrict__ h_out,
                 const float* __restrict__ Wl,
                 const float* __restrict__ bl,
                 const float* __restrict__ Wr,
                 const float* __restrict__ gamma,
                 const float* __restrict__ beta) {
    __shared__ float red_s[4][NPB][2];

    const int tid  = threadIdx.x;
    const int lane = tid & 63;
    const int wave = tid >> 6;
    const int n0   = blockIdx.x * NPB;

    const int jb = wave * 32;                          // wave-uniform j-tile base
    const float* __restrict__ Wlb = Wl + jb * D;
    const float* __restrict__ Wrb = Wr + jb * D;

    const int node  = n0 + lane;
    const int nodec = min(node, N_NODES - 1);
    const float* __restrict__ hrow = h + (size_t)nodec * D;
    const float* __restrict__ mrow = mean + (size_t)nodec * D;

    float acc[32];
    #pragma unroll
    for (int jj = 0; jj < 32; ++jj) acc[jj] = bl[jb + jj];

    #pragma unroll 1
    for (int kc = 0; kc < D; kc += 16) {
        const float4 m0 = *reinterpret_cast<const float4*>(mrow + kc);
        const float4 m1 = *reinterpret_cast<const float4*>(mrow + kc + 4);
        const float4 m2 = *reinterpret_cast<const float4*>(mrow + kc + 8);
        const float4 m3 = *reinterpret_cast<const float4*>(mrow + kc + 12);
        const float4 x0 = *reinterpret_cast<const float4*>(hrow + kc);
        const float4 x1 = *reinterpret_cast<const float4*>(hrow + kc + 4);
        const float4 x2 = *reinterpret_cast<const float4*>(hrow + kc + 8);
        const float4 x3 = *reinterpret_cast<const float4*>(hrow + kc + 12);

        #pragma unroll 4
        for (int jj = 0; jj < 32; ++jj) {
            const float* wlp = Wlb + jj * D + kc;      // uniform -> s_load_dwordx4
            const float* wrp = Wrb + jj * D + kc;
            const float4 wl0 = *reinterpret_cast<const float4*>(wlp);
            const float4 wl1 = *reinterpret_cast<const float4*>(wlp + 4);
            const float4 wl2 = *reinterpret_cast<const float4*>(wlp + 8);
            const float4 wl3 = *reinterpret_cast<const float4*>(wlp + 12);
            const float4 wr0 = *reinterpret_cast<const float4*>(wrp);
            const float4 wr1 = *reinterpret_cast<const float4*>(wrp + 4);
            const float4 wr2 = *reinterpret_cast<const float4*>(wrp + 8);
            const float4 wr3 = *reinterpret_cast<const float4*>(wrp + 12);
            float a = acc[jj];
            a = fmaf(m0.x, wl0.x, a); a = fmaf(m0.y, wl0.y, a);
            a = fmaf(m0.z, wl0.z, a); a = fmaf(m0.w, wl0.w, a);
            a = fmaf(m1.x, wl1.x, a); a = fmaf(m1.y, wl1.y, a);
            a = fmaf(m1.z, wl1.z, a); a = fmaf(m1.w, wl1.w, a);
            a = fmaf(m2.x, wl2.x, a); a = fmaf(m2.y, wl2.y, a);
            a = fmaf(m2.z, wl2.z, a); a = fmaf(m2.w, wl2.w, a);
            a = fmaf(m3.x, wl3.x, a); a = fmaf(m3.y, wl3.y, a);
            a = fmaf(m3.z, wl3.z, a); a = fmaf(m3.w, wl3.w, a);
            a = fmaf(x0.x, wr0.x, a); a = fmaf(x0.y, wr0.y, a);
            a = fmaf(x0.z, wr0.z, a); a = fmaf(x0.w, wr0.w, a);
            a = fmaf(x1.x, wr1.x, a); a = fmaf(x1.y, wr1.y, a);
            a = fmaf(x1.z, wr1.z, a); a = fmaf(x1.w, wr1.w, a);
            a = fmaf(x2.x, wr2.x, a); a = fmaf(x2.y, wr2.y, a);
            a = fmaf(x2.z, wr2.z, a); a = fmaf(x2.w, wr2.w, a);
            a = fmaf(x3.x, wr3.x, a); a = fmaf(x3.y, wr3.y, a);
            a = fmaf(x3.z, wr3.z, a); a = fmaf(x3.w, wr3.w, a);
            acc[jj] = a;
        }
    }

    // ---- LayerNorm + ReLU + residual ----
    float sum = 0.f, sq = 0.f;
    #pragma unroll
    for (int jj = 0; jj < 32; ++jj) {
        sum += acc[jj];
        sq   = fmaf(acc[jj], acc[jj], sq);
    }
    red_s[wave][lane][0] = sum;
    red_s[wave][lane][1] = sq;
    __syncthreads();
    float ts = 0.f, tq = 0.f;
    #pragma unroll
    for (int w2 = 0; w2 < 4; ++w2) {
        ts += red_s[w2][lane][0];
        tq += red_s[w2][lane][1];
    }
    const float mu   = ts * (1.f / 128.f);
    const float var  = fmaf(tq, 1.f / 128.f, -mu * mu);
    const float rstd = 1.f / sqrtf(var + EPS);

    if (node < N_NODES) {
        float* orow = h_out + (size_t)node * D + jb;
        const float* hres = hrow + jb;
        #pragma unroll
        for (int q = 0; q < 8; ++q) {
            const float4 hv = *reinterpret_cast<const float4*>(hres + q * 4);
            const float g0 = gamma[jb + q * 4 + 0], b0 = beta[jb + q * 4 + 0];
            const float g1 = gamma[jb + q * 4 + 1], b1 = beta[jb + q * 4 + 1];
            const float g2 = gamma[jb + q * 4 + 2], b2 = beta[jb + q * 4 + 2];
            const float g3 = gamma[jb + q * 4 + 3], b3 = beta[jb + q * 4 + 3];
            float4 o;
            o.x = hv.x + fmaxf((acc[q * 4 + 0] - mu) * rstd * g0 + b0, 0.f);
            o.y = hv.y + fmaxf((acc[q * 4 + 1] - mu) * rstd * g1 + b1, 0.f);
            o.z = hv.z + fmaxf((acc[q * 4 + 2] - mu) * rstd * g2 + b2, 0.f);
            o.w = hv.w + fmaxf((acc[q * 4 + 3] - mu) * rstd * g3 + b3, 0.f);
            *reinterpret_cast<float4*>(orow + q * 4) = o;
        }
    }
}

// ---------------- launch ----------------

extern "C" void kernel_launch(void* const* d_in, const int* in_sizes, int n_in,
                              void* d_out, int out_size, void* d_ws, size_t ws_size,
                              hipStream_t stream) {
    const float* nf = (const float*)d_in[0];
    const int*   ei = (const int*)d_in[1];        // [2][E]: src row, dst row
    const float* Wl = (const float*)d_in[2];      // [3][128][128]
    const float* bl = (const float*)d_in[3];      // [3][128]
    const float* Wr = (const float*)d_in[4];
    const float* gm = (const float*)d_in[5];
    const float* bt = (const float*)d_in[6];
    float* out = (float*)d_out;

    char* w = (char*)d_ws;
    size_t off = 0;
    auto carve = [&](size_t bytes) -> char* {
        char* p = w + off;
        off = (off + bytes + 511) & ~(size_t)511;
        return p;
    };
    int*   deg       = (int*)carve((size_t)N_NODES * 4);
    int*   row_start = (int*)carve((size_t)(N_NODES + 1) * 4);
    int*   cursor    = (int*)carve((size_t)N_NODES * 4);
    int*   bsum      = (int*)carve((size_t)SCAN_B * 4);
    int*   bbase     = (int*)carve((size_t)SCAN_B * 4);
    int*   ssrc      = (int*)carve((size_t)N_EDGES * 4);
    float* hA        = (float*)carve((size_t)N_NODES * D * 4);
    float* hB        = (float*)carve((size_t)N_NODES * D * 4);
    float* meanb     = (float*)carve((size_t)N_NODES * D * 4);

    const int* src = ei;
    const int* dst = ei + N_EDGES;

    hipMemsetAsync(deg, 0, (size_t)N_NODES * 4, stream);
    count_kernel<<<(N_EDGES + 255) / 256, 256, 0, stream>>>(dst, deg);
    block_reduce_kernel<<<SCAN_B, 256, 0, stream>>>(deg, bsum);
    block_scan_kernel<<<1, 256, 0, stream>>>(bsum, bbase);
    expand_kernel<<<SCAN_B, 256, 0, stream>>>(deg, bbase, row_start, cursor);
    fill_kernel<<<(N_EDGES + 255) / 256, 256, 0, stream>>>(src, dst, cursor, ssrc);

    const int GA = (N_NODES + 3) / 4;           // 12500
    const int GB = (N_NODES + NPB - 1) / NPB;   // 782

    agg_kernel<<<GA, THREADS, 0, stream>>>(nf, meanb, row_start, ssrc);
    gemm_kernel<<<GB, THREADS, 0, stream>>>(nf, meanb, hA, Wl, bl, Wr, gm, bt);

    agg_kernel<<<GA, THREADS, 0, stream>>>(hA, meanb, row_start, ssrc);
    gemm_kernel<<<GB, THREADS, 0, stream>>>(hA, meanb, hB,
                                            Wl + D * D, bl + D, Wr + D * D, gm + D, bt + D);

    agg_kernel<<<GA, THREADS, 0, stream>>>(hB, meanb, row_start, ssrc);
    gemm_kernel<<<GB, THREADS, 0, stream>>>(hB, meanb, out,
                                            Wl + 2 * D * D, bl + 2 * D, Wr + 2 * D * D,
                                            gm + 2 * D, bt + 2 * D);
}

// Round 5
// 566.576 us; speedup vs baseline: 5.6793x; 2.0089x over previous
//
#include <hip/hip_runtime.h>

#define N_NODES 50000
#define N_EDGES 800000
#define D       128
#define THREADS 256
#define EPS     1e-5f
#define SCAN_B  196     // ceil(N_NODES/256)
#define MTILES  3125    // N_NODES / 16

typedef __attribute__((ext_vector_type(8))) __bf16  bf16x8;
typedef __attribute__((ext_vector_type(8))) short   short8;
typedef __attribute__((ext_vector_type(4))) float   f32x4;
typedef __attribute__((ext_vector_type(4))) unsigned int u32x4;

// pack fp32 -> (bf16_hi << 16) | bf16_lo  (bf16x2 split: hi+lo ~= x to ~2^-17 rel)
__device__ inline unsigned int packbf(float x) {
    unsigned int u  = __float_as_uint(x);
    unsigned int hi = (u + 0x7FFFu + ((u >> 16) & 1u)) >> 16;
    float hf = __uint_as_float(hi << 16);
    float lo = x - hf;
    unsigned int ul  = __float_as_uint(lo);
    unsigned int l16 = (ul + 0x7FFFu + ((ul >> 16) & 1u)) >> 16;
    return (hi << 16) | (l16 & 0xFFFFu);
}
__device__ inline float unpackbf(unsigned int u) {
    return __uint_as_float(u & 0xFFFF0000u) + __uint_as_float(u << 16);
}

// ---------------- CSR build ----------------

__global__ void count_kernel(const int* __restrict__ dst, int* __restrict__ deg) {
    int e = blockIdx.x * 256 + threadIdx.x;
    if (e < N_EDGES) atomicAdd(&deg[dst[e]], 1);
}

__global__ void block_reduce_kernel(const int* __restrict__ deg, int* __restrict__ bsum) {
    __shared__ int red[256];
    int i = blockIdx.x * 256 + threadIdx.x;
    red[threadIdx.x] = (i < N_NODES) ? deg[i] : 0;
    __syncthreads();
    for (int off = 128; off > 0; off >>= 1) {
        if (threadIdx.x < off) red[threadIdx.x] += red[threadIdx.x + off];
        __syncthreads();
    }
    if (threadIdx.x == 0) bsum[blockIdx.x] = red[0];
}

__global__ void block_scan_kernel(const int* __restrict__ bsum, int* __restrict__ bbase) {
    __shared__ int s[256];
    const int t = threadIdx.x;
    const int v = (t < SCAN_B) ? bsum[t] : 0;
    s[t] = v;
    __syncthreads();
    for (int off = 1; off < 256; off <<= 1) {
        int add = (t >= off) ? s[t - off] : 0;
        __syncthreads();
        s[t] += add;
        __syncthreads();
    }
    if (t < SCAN_B) bbase[t] = s[t] - v;   // exclusive
}

__global__ void expand_kernel(const int* __restrict__ deg, const int* __restrict__ bbase,
                              int* __restrict__ row_start, int* __restrict__ cursor) {
    __shared__ int s[256];
    const int t = threadIdx.x;
    const int i = blockIdx.x * 256 + t;
    const int v = (i < N_NODES) ? deg[i] : 0;
    s[t] = v;
    __syncthreads();
    for (int off = 1; off < 256; off <<= 1) {
        int add = (t >= off) ? s[t - off] : 0;
        __syncthreads();
        s[t] += add;
        __syncthreads();
    }
    const int excl = bbase[blockIdx.x] + s[t] - v;
    if (i < N_NODES) { row_start[i] = excl; cursor[i] = excl; }
    if (i == N_NODES - 1) row_start[N_NODES] = excl + v;
}

__global__ void fill_kernel(const int* __restrict__ src, const int* __restrict__ dst,
                            int* __restrict__ cursor, int* __restrict__ ssrc) {
    int e = blockIdx.x * 256 + threadIdx.x;
    if (e < N_EDGES) {
        int d = dst[e];
        int p = atomicAdd(&cursor[d], 1);
        ssrc[p] = src[e];
    }
}

// ---------------- prep: weights + layer-0 h into packed/bf16 form ----------

// Whi/Wlo: [3][128][256] ushort, row j = concat(Wl[j][:], Wr[j][:])
__global__ void wprep_kernel(const float* __restrict__ Wl, const float* __restrict__ Wr,
                             unsigned short* __restrict__ Whi, unsigned short* __restrict__ Wlo) {
    int t = blockIdx.x * 256 + threadIdx.x;
    if (t >= 3 * 128 * 256) return;
    const int L = t >> 15;
    const int r = t & 32767;
    const int j = r >> 8;
    const int k = r & 255;
    const float x = (k < 128) ? Wl[((size_t)L * 128 + j) * 128 + k]
                              : Wr[((size_t)L * 128 + j) * 128 + (k - 128)];
    const unsigned int p = packbf(x);
    Whi[t] = (unsigned short)(p >> 16);
    Wlo[t] = (unsigned short)(p & 0xFFFFu);
}

// layer-0 h (node_features fp32) -> packed h-part of A (k in [128,256))
__global__ void cvt0_kernel(const float* __restrict__ nf, unsigned int* __restrict__ Apk) {
    int t = blockIdx.x * 256 + threadIdx.x;   // one thread per 4 elems
    if (t >= N_NODES * 32) return;
    const int n  = t >> 5;
    const int k4 = (t & 31) * 4;
    const float4 v = *reinterpret_cast<const float4*>(nf + (size_t)n * D + k4);
    u32x4 o;
    o.x = packbf(v.x); o.y = packbf(v.y); o.z = packbf(v.z); o.w = packbf(v.w);
    *reinterpret_cast<u32x4*>(Apk + (size_t)n * 256 + 128 + k4) = o;
}

// copy gemm's packed h_out into the h-part of A (row stride 128 -> 256)
__global__ void copy_kernel(unsigned int* __restrict__ Apk, const unsigned int* __restrict__ Hn) {
    int t = blockIdx.x * 256 + threadIdx.x;
    if (t >= N_NODES * 32) return;
    const int n  = t >> 5;
    const int k4 = (t & 31) * 4;
    *reinterpret_cast<u32x4*>(Apk + (size_t)n * 256 + 128 + k4) =
        *reinterpret_cast<const u32x4*>(Hn + (size_t)n * D + k4);
}

// ---------------- aggregation: mean part of A (k in [0,128)) ----------------
// Wave-per-node; gathers packed h rows (512B/row, uint2 per lane), scalar
// edge indices, 8-edge clamped+weighted chunks; writes packed mean.

__global__ __launch_bounds__(256, 8)
void agg_kernel(unsigned int* __restrict__ Apk,
                const int* __restrict__ row_start, const int* __restrict__ ssrc) {
    const int lane = threadIdx.x & 63;
    const int wave = threadIdx.x >> 6;
    const int n = blockIdx.x * 4 + wave;
    if (n >= N_NODES) return;
    const int e0 = __builtin_amdgcn_readfirstlane(row_start[n]);
    const int e1 = __builtin_amdgcn_readfirstlane(row_start[n + 1]);
    const int off = lane * 2;
    const unsigned int* __restrict__ H = Apk + 128 + off;   // h-part, row stride 256

    float a0 = 0.f, a1 = 0.f;
    #pragma unroll 1
    for (int e = e0; e < e1; e += 8) {
        const int el = e1 - 1;
        const int s0 = ssrc[min(e + 0, el)];
        const int s1 = ssrc[min(e + 1, el)];
        const int s2 = ssrc[min(e + 2, el)];
        const int s3 = ssrc[min(e + 3, el)];
        const int s4 = ssrc[min(e + 4, el)];
        const int s5 = ssrc[min(e + 5, el)];
        const int s6 = ssrc[min(e + 6, el)];
        const int s7 = ssrc[min(e + 7, el)];
        const uint2 v0 = *reinterpret_cast<const uint2*>(H + (size_t)s0 * 256);
        const uint2 v1 = *reinterpret_cast<const uint2*>(H + (size_t)s1 * 256);
        const uint2 v2 = *reinterpret_cast<const uint2*>(H + (size_t)s2 * 256);
        const uint2 v3 = *reinterpret_cast<const uint2*>(H + (size_t)s3 * 256);
        const uint2 v4 = *reinterpret_cast<const uint2*>(H + (size_t)s4 * 256);
        const uint2 v5 = *reinterpret_cast<const uint2*>(H + (size_t)s5 * 256);
        const uint2 v6 = *reinterpret_cast<const uint2*>(H + (size_t)s6 * 256);
        const uint2 v7 = *reinterpret_cast<const uint2*>(H + (size_t)s7 * 256);
        const float w1 = (e + 1 < e1) ? 1.f : 0.f;
        const float w2 = (e + 2 < e1) ? 1.f : 0.f;
        const float w3 = (e + 3 < e1) ? 1.f : 0.f;
        const float w4 = (e + 4 < e1) ? 1.f : 0.f;
        const float w5 = (e + 5 < e1) ? 1.f : 0.f;
        const float w6 = (e + 6 < e1) ? 1.f : 0.f;
        const float w7 = (e + 7 < e1) ? 1.f : 0.f;
        a0 += unpackbf(v0.x);                    a1 += unpackbf(v0.y);
        a0 = fmaf(unpackbf(v1.x), w1, a0);       a1 = fmaf(unpackbf(v1.y), w1, a1);
        a0 = fmaf(unpackbf(v2.x), w2, a0);       a1 = fmaf(unpackbf(v2.y), w2, a1);
        a0 = fmaf(unpackbf(v3.x), w3, a0);       a1 = fmaf(unpackbf(v3.y), w3, a1);
        a0 = fmaf(unpackbf(v4.x), w4, a0);       a1 = fmaf(unpackbf(v4.y), w4, a1);
        a0 = fmaf(unpackbf(v5.x), w5, a0);       a1 = fmaf(unpackbf(v5.y), w5, a1);
        a0 = fmaf(unpackbf(v6.x), w6, a0);       a1 = fmaf(unpackbf(v6.y), w6, a1);
        a0 = fmaf(unpackbf(v7.x), w7, a0);       a1 = fmaf(unpackbf(v7.y), w7, a1);
    }
    const float inv = 1.f / (float)max(e1 - e0, 1);
    uint2 w;
    w.x = packbf(a0 * inv);
    w.y = packbf(a1 * inv);
    *reinterpret_cast<uint2*>(Apk + (size_t)n * 256 + off) = w;
}

// ---------------- MFMA GEMM + LN + ReLU + residual ----------------
// Wave = one 16-node M-tile; K=256 (mean|h), N=128. bf16x3 split product:
// out = A@Wcat^T via AH*BH + AL*BH + AH*BL. Fragment layout (gfx950
// 16x16x32): A row=lane&15, k=(lane>>4)*8+i; B col=lane&15, same k;
// C/D col=lane&15, row=(lane>>4)*4+reg [m89-verified].

template<int MODE>   // 0: write packed h_out to Hnext; 1: write fp32 to outF
__global__ __launch_bounds__(256, 3)
void gemm_kernel(const unsigned int* __restrict__ Apk,
                 unsigned int* __restrict__ Hnext,
                 float* __restrict__ outF,
                 const unsigned short* __restrict__ Whi,
                 const unsigned short* __restrict__ Wlo,
                 const float* __restrict__ bl,
                 const float* __restrict__ gamma,
                 const float* __restrict__ beta) {
    const int lane = threadIdx.x & 63;
    const int wave = threadIdx.x >> 6;
    const int mt = blockIdx.x * 4 + wave;
    if (mt >= MTILES) return;
    const int rl = lane & 15;
    const int kg = lane >> 4;
    const int n  = mt * 16 + rl;

    // ---- load + unpack A fragments (8 K-tiles, hi & lo) ----
    bf16x8 AH[8], AL[8];
    const unsigned int* __restrict__ ar = Apk + (size_t)n * 256 + kg * 8;
    #pragma unroll
    for (int kt = 0; kt < 8; ++kt) {
        const u32x4 p = *reinterpret_cast<const u32x4*>(ar + kt * 32);
        const u32x4 q = *reinterpret_cast<const u32x4*>(ar + kt * 32 + 4);
        u32x4 hw, lw;
        hw.x = (p.y & 0xFFFF0000u) | (p.x >> 16);
        hw.y = (p.w & 0xFFFF0000u) | (p.z >> 16);
        hw.z = (q.y & 0xFFFF0000u) | (q.x >> 16);
        hw.w = (q.w & 0xFFFF0000u) | (q.z >> 16);
        lw.x = (p.x & 0xFFFFu) | (p.y << 16);
        lw.y = (p.z & 0xFFFFu) | (p.w << 16);
        lw.z = (q.x & 0xFFFFu) | (q.y << 16);
        lw.w = (q.z & 0xFFFFu) | (q.w << 16);
        AH[kt] = __builtin_bit_cast(bf16x8, hw);
        AL[kt] = __builtin_bit_cast(bf16x8, lw);
    }

    f32x4 AC[8];
    #pragma unroll
    for (int jt = 0; jt < 8; ++jt) { AC[jt].x = 0.f; AC[jt].y = 0.f; AC[jt].z = 0.f; AC[jt].w = 0.f; }

    #pragma unroll
    for (int jt = 0; jt < 8; ++jt) {
        const unsigned short* __restrict__ bhp = Whi + (size_t)(jt * 16 + rl) * 256 + kg * 8;
        const unsigned short* __restrict__ blp = Wlo + (size_t)(jt * 16 + rl) * 256 + kg * 8;
        #pragma unroll
        for (int kt = 0; kt < 8; ++kt) {
            const bf16x8 BH = __builtin_bit_cast(bf16x8, *reinterpret_cast<const short8*>(bhp + kt * 32));
            const bf16x8 BL = __builtin_bit_cast(bf16x8, *reinterpret_cast<const short8*>(blp + kt * 32));
            AC[jt] = __builtin_amdgcn_mfma_f32_16x16x32_bf16(AH[kt], BH, AC[jt], 0, 0, 0);
            AC[jt] = __builtin_amdgcn_mfma_f32_16x16x32_bf16(AL[kt], BH, AC[jt], 0, 0, 0);
            AC[jt] = __builtin_amdgcn_mfma_f32_16x16x32_bf16(AH[kt], BL, AC[jt], 0, 0, 0);
        }
    }

    // ---- bias ----
    #pragma unroll
    for (int jt = 0; jt < 8; ++jt) {
        const float bb = bl[jt * 16 + rl];
        AC[jt].x += bb; AC[jt].y += bb; AC[jt].z += bb; AC[jt].w += bb;
    }

    // ---- LayerNorm stats: row = mt*16 + kg*4 + r, spread over 16 lanes (rl) x 8 jt
    float mu[4], rs[4];
    #pragma unroll
    for (int r = 0; r < 4; ++r) {
        float s1 = 0.f, s2 = 0.f;
        #pragma unroll
        for (int jt = 0; jt < 8; ++jt) {
            const float v = AC[jt][r];
            s1 += v;
            s2 = fmaf(v, v, s2);
        }
        #pragma unroll
        for (int m = 1; m < 16; m <<= 1) {
            s1 += __shfl_xor(s1, m);
            s2 += __shfl_xor(s2, m);
        }
        mu[r] = s1 * (1.f / 128.f);
        const float var = fmaf(s2, 1.f / 128.f, -mu[r] * mu[r]);
        rs[r] = 1.f / sqrtf(var + EPS);
    }

    // ---- LN + ReLU + residual + store ----
    #pragma unroll
    for (int jt = 0; jt < 8; ++jt) {
        const int j = jt * 16 + rl;
        const float g  = gamma[j];
        const float be = beta[j];
        #pragma unroll
        for (int r = 0; r < 4; ++r) {
            const int row = mt * 16 + kg * 4 + r;
            const float res = unpackbf(Apk[(size_t)row * 256 + 128 + j]);
            const float v = fmaxf(fmaf((AC[jt][r] - mu[r]) * rs[r], g, be), 0.f);
            const float o = res + v;
            if (MODE == 0) Hnext[(size_t)row * D + j] = packbf(o);
            else           outF [(size_t)row * D + j] = o;
        }
    }
}

// ---------------- launch ----------------

extern "C" void kernel_launch(void* const* d_in, const int* in_sizes, int n_in,
                              void* d_out, int out_size, void* d_ws, size_t ws_size,
                              hipStream_t stream) {
    const float* nf = (const float*)d_in[0];
    const int*   ei = (const int*)d_in[1];        // [2][E]: src row, dst row
    const float* Wl = (const float*)d_in[2];      // [3][128][128]
    const float* bl = (const float*)d_in[3];      // [3][128]
    const float* Wr = (const float*)d_in[4];
    const float* gm = (const float*)d_in[5];
    const float* bt = (const float*)d_in[6];
    float* out = (float*)d_out;

    char* w = (char*)d_ws;
    size_t off = 0;
    auto carve = [&](size_t bytes) -> char* {
        char* p = w + off;
        off = (off + bytes + 511) & ~(size_t)511;
        return p;
    };
    int*   deg       = (int*)carve((size_t)N_NODES * 4);
    int*   row_start = (int*)carve((size_t)(N_NODES + 1) * 4);
    int*   cursor    = (int*)carve((size_t)N_NODES * 4);
    int*   bsum      = (int*)carve((size_t)SCAN_B * 4);
    int*   bbase     = (int*)carve((size_t)SCAN_B * 4);
    int*   ssrc      = (int*)carve((size_t)N_EDGES * 4);
    unsigned int*   Apk   = (unsigned int*)carve((size_t)N_NODES * 256 * 4);   // 51.2 MB
    unsigned int*   Hnext = (unsigned int*)carve((size_t)N_NODES * D * 4);     // 25.6 MB
    unsigned short* Whi   = (unsigned short*)carve((size_t)3 * 128 * 256 * 2);
    unsigned short* Wlo   = (unsigned short*)carve((size_t)3 * 128 * 256 * 2);

    const int* src = ei;
    const int* dst = ei + N_EDGES;

    hipMemsetAsync(deg, 0, (size_t)N_NODES * 4, stream);
    count_kernel<<<(N_EDGES + 255) / 256, 256, 0, stream>>>(dst, deg);
    block_reduce_kernel<<<SCAN_B, 256, 0, stream>>>(deg, bsum);
    block_scan_kernel<<<1, 256, 0, stream>>>(bsum, bbase);
    expand_kernel<<<SCAN_B, 256, 0, stream>>>(deg, bbase, row_start, cursor);
    fill_kernel<<<(N_EDGES + 255) / 256, 256, 0, stream>>>(src, dst, cursor, ssrc);

    wprep_kernel<<<(3 * 128 * 256 + 255) / 256, 256, 0, stream>>>(Wl, Wr, Whi, Wlo);
    cvt0_kernel<<<(N_NODES * 32 + 255) / 256, 256, 0, stream>>>(nf, Apk);

    const int GA = (N_NODES + 3) / 4;        // 12500
    const int GG = (MTILES + 3) / 4;         // 782
    const int GC = (N_NODES * 32 + 255) / 256;

    // layer 0
    agg_kernel<<<GA, THREADS, 0, stream>>>(Apk, row_start, ssrc);
    gemm_kernel<0><<<GG, THREADS, 0, stream>>>(Apk, Hnext, nullptr,
                                               Whi, Wlo, bl, gm, bt);
    copy_kernel<<<GC, 256, 0, stream>>>(Apk, Hnext);
    // layer 1
    agg_kernel<<<GA, THREADS, 0, stream>>>(Apk, row_start, ssrc);
    gemm_kernel<0><<<GG, THREADS, 0, stream>>>(Apk, Hnext, nullptr,
                                               Whi + 32768, Wlo + 32768,
                                               bl + D, gm + D, bt + D);
    copy_kernel<<<GC, 256, 0, stream>>>(Apk, Hnext);
    // layer 2
    agg_kernel<<<GA, THREADS, 0, stream>>>(Apk, row_start, ssrc);
    gemm_kernel<1><<<GG, THREADS, 0, stream>>>(Apk, nullptr, out,
                                               Whi + 65536, Wlo + 65536,
                                               bl + 2 * D, gm + 2 * D, bt + 2 * D);
}